// Round 2
// baseline (863.176 us; speedup 1.0000x reference)
//
#include <hip/hip_runtime.h>
#include <hip/hip_bf16.h>
#include <math.h>
#include <stdint.h>

#define NN 50000
#define NE 500000
#define DIN 264
#define KP1 288      // DIN padded to multiple of 32
#define HID 128
#define EDIM 16

#define NSH 64       // work-distribution shards for k_fused_agg
#define SHSZ 782     // ceil(NN / NSH)

typedef __attribute__((ext_vector_type(8))) short short8;
typedef __attribute__((ext_vector_type(4))) float f32x4;

__device__ __forceinline__ short f2bf(float v) {
    union { float f; unsigned u; } x; x.f = v;
    unsigned r = x.u + 0x7fff + ((x.u >> 16) & 1);
    return (short)(r >> 16);
}
__device__ __forceinline__ float bf2f(short v) {
    union { float f; unsigned u; } x;
    x.u = ((unsigned)(unsigned short)v) << 16;
    return x.f;
}
// unpack two bf16 packed in a dword
__device__ __forceinline__ float bflo(unsigned u) {
    union { float f; unsigned u; } x; x.u = u << 16; return x.f;
}
__device__ __forceinline__ float bfhi(unsigned u) {
    union { float f; unsigned u; } x; x.u = u & 0xffff0000u; return x.f;
}

__device__ __forceinline__ void gload_lds16(const void* g, void* l) {
    __builtin_amdgcn_global_load_lds(
        (const __attribute__((address_space(1))) unsigned int*)g,
        (__attribute__((address_space(3))) unsigned int*)l, 16, 0, 0);
}

// ---------------- CSR build (dst -> in-edges) ----------------
__global__ void k_count(const int* __restrict__ dst, int* __restrict__ cnt) {
    int e = blockIdx.x * blockDim.x + threadIdx.x;
    if (e < NE) atomicAdd(&cnt[dst[e]], 1);
}

__global__ __launch_bounds__(256) void k_scan1(const int* __restrict__ cnt,
                                               int* __restrict__ off, int* __restrict__ bsum) {
    __shared__ int buf[256];
    int b = blockIdx.x, t = threadIdx.x;
    int i = b * 256 + t;
    int v = (i < NN) ? cnt[i] : 0;
    buf[t] = v; __syncthreads();
    for (int s = 1; s < 256; s <<= 1) {
        int u = (t >= s) ? buf[t - s] : 0; __syncthreads();
        buf[t] += u; __syncthreads();
    }
    if (i < NN) off[i + 1] = buf[t];
    if (t == 255) bsum[b] = buf[255];
}

__global__ void k_scan2(int* __restrict__ bsum, int nb) {
    __shared__ int buf[256];
    int t = threadIdx.x;
    int o = (t < nb) ? bsum[t] : 0;
    buf[t] = o; __syncthreads();
    for (int s = 1; s < 256; s <<= 1) {
        int u = (t >= s) ? buf[t - s] : 0; __syncthreads();
        buf[t] += u; __syncthreads();
    }
    if (t < nb) bsum[t] = buf[t] - o;   // exclusive
}

// finalize offsets AND copy to cur in one pass
__global__ void k_scan3c(int* __restrict__ off, const int* __restrict__ bsum,
                         int* __restrict__ cur) {
    int j = blockIdx.x * 256 + threadIdx.x;   // 0..NN
    if (j > NN) return;
    int v = (j == 0) ? 0 : off[j] + bsum[(j - 1) >> 8];
    off[j] = v;
    if (j < NN) cur[j] = v;
}

__global__ void k_scatter(const int* __restrict__ src, const int* __restrict__ dst,
                          int* __restrict__ cur, int2* __restrict__ csr_se) {
    int e = blockIdx.x * blockDim.x + threadIdx.x;
    if (e < NE) {
        int d = dst[e];
        int p = atomicAdd(&cur[d], 1);
        csr_se[p] = make_int2(src[e], e);
    }
}

// ---------------- weight/bias/input prep ----------------
__global__ void k_cvt_x(const float* __restrict__ x, short* __restrict__ xb) {
    int idx = blockIdx.x * 256 + threadIdx.x;
    if (idx >= NN * KP1) return;
    int i = idx / KP1, k = idx - i * KP1;
    xb[idx] = (k < DIN) ? f2bf(x[(size_t)i * DIN + k]) : (short)0;
}

// all weight transposes + bias concats in ONE dispatch
__global__ void k_prep_w(const float* __restrict__ Wl1, const float* __restrict__ Wr1,
                         const float* __restrict__ Wres, const float* __restrict__ Wl2,
                         const float* __restrict__ Wr2, const float* __restrict__ Wout,
                         const float* __restrict__ bl1, const float* __restrict__ br1,
                         const float* __restrict__ bres, const float* __restrict__ bl2,
                         const float* __restrict__ br2,
                         short* __restrict__ Wt1, short* __restrict__ Wt2,
                         short* __restrict__ Wt3, float* __restrict__ bcat1,
                         float* __restrict__ bcat2) {
    int idx = blockIdx.x * 256 + threadIdx.x;
    if (idx < 384 * KP1) {
        int n = idx / KP1, k = idx - n * KP1;
        float v = 0.f;
        if (k < DIN) {
            const float* W = (n < 128) ? Wl1 : ((n < 256) ? Wr1 : Wres);
            v = W[(size_t)k * 128 + (n & 127)];
        }
        Wt1[idx] = f2bf(v);
        return;
    }
    idx -= 384 * KP1;
    if (idx < 256 * 128) {
        int n = idx >> 7, k = idx & 127;
        const float* W = (n < 128) ? Wl2 : Wr2;
        Wt2[idx] = f2bf(W[(size_t)k * 128 + (n & 127)]);
        return;
    }
    idx -= 256 * 128;
    if (idx < 128 * 128) {
        int n = idx >> 7, k = idx & 127;
        Wt3[idx] = f2bf(Wout[(size_t)k * 128 + n]);
        return;
    }
    idx -= 128 * 128;
    if (idx < 384) {
        bcat1[idx] = (idx < 128) ? bl1[idx] : ((idx < 256) ? br1[idx - 128] : bres[idx - 256]);
        return;
    }
    idx -= 384;
    if (idx < 256)
        bcat2[idx] = (idx < 128) ? bl2[idx] : br2[idx - 128];
}

// ---------------- bf16 MFMA GEMM: C[M x NS] = A[M x Kpad] @ Bt[NS x Kpad]^T + bias ----------------
template <bool BF16OUT>
__global__ __launch_bounds__(256) void k_mfma_gemm(const short* __restrict__ A,
                                                   const short* __restrict__ Bt,
                                                   const float* __restrict__ bias,
                                                   float* __restrict__ Cf,
                                                   short* __restrict__ Cb,
                                                   int M, int Kpad, int NS) {
    __shared__ short As[128 * 32];
    __shared__ short Bs[128 * 32];
    int t = threadIdx.x;
    int lane = t & 63, wid = t >> 6;
    int wm = (wid & 1) * 64, wn = (wid >> 1) * 64;
    int cl = lane & 15, quad = lane >> 4;
    int row0 = blockIdx.x * 128;
    int col0 = blockIdx.y * 128;

    f32x4 acc[4][4];
#pragma unroll
    for (int i = 0; i < 4; ++i)
#pragma unroll
        for (int j = 0; j < 4; ++j) acc[i][j] = (f32x4)0.f;

    for (int k0 = 0; k0 < Kpad; k0 += 32) {
#pragma unroll
        for (int r = 0; r < 2; ++r) {
            int c = t + r * 256;                     // chunk 0..511
            int m = c >> 2;
            int row = row0 + m; if (row >= M) row = M - 1;
            const char* ga = (const char*)A + ((size_t)row * Kpad + k0) * 2 + (c & 3) * 16;
            gload_lds16(ga, (char*)As + c * 16);
            int n = col0 + m;
            const char* gb = (const char*)Bt + ((size_t)n * Kpad + k0) * 2 + (c & 3) * 16;
            gload_lds16(gb, (char*)Bs + c * 16);
        }
        __syncthreads();

        short8 a[4], b[4];
#pragma unroll
        for (int mi = 0; mi < 4; ++mi)
            a[mi] = *(const short8*)&As[(wm + mi * 16 + cl) * 32 + quad * 8];
#pragma unroll
        for (int ni = 0; ni < 4; ++ni)
            b[ni] = *(const short8*)&Bs[(wn + ni * 16 + cl) * 32 + quad * 8];
#pragma unroll
        for (int mi = 0; mi < 4; ++mi)
#pragma unroll
            for (int ni = 0; ni < 4; ++ni)
                acc[mi][ni] = __builtin_amdgcn_mfma_f32_16x16x32_bf16(a[mi], b[ni], acc[mi][ni], 0, 0, 0);
        __syncthreads();
    }

#pragma unroll
    for (int mi = 0; mi < 4; ++mi)
#pragma unroll
        for (int ni = 0; ni < 4; ++ni) {
            int col = col0 + wn + ni * 16 + cl;
            float bv = bias[col];
#pragma unroll
            for (int r = 0; r < 4; ++r) {
                int row = row0 + wm + mi * 16 + quad * 4 + r;
                if (row < M) {
                    float v = acc[mi][ni][r] + bv;
                    if (BF16OUT) Cb[(size_t)row * NS + col] = f2bf(v);
                    else         Cf[(size_t)row * NS + col] = v;
                }
            }
        }
}

// ---------------- GEMM (M x 128 @ 128x128) with fused LayerNorm epilogue ----------------
__global__ __launch_bounds__(256) void k_gemm_ln(const short* __restrict__ A,
                                                 const short* __restrict__ Bt,
                                                 const float* __restrict__ bias,
                                                 const float* __restrict__ gamma,
                                                 const float* __restrict__ beta,
                                                 float* __restrict__ out, int M) {
    __shared__ short As[128 * 32];
    __shared__ short Bs[128 * 32];
    __shared__ float redS[128][2];
    int t = threadIdx.x;
    int lane = t & 63, wid = t >> 6;
    int wm = (wid & 1) * 64, wn = (wid >> 1) * 64;
    int cl = lane & 15, quad = lane >> 4;
    int row0 = blockIdx.x * 128;
    int wh = wid >> 1;                 // which 64-col half this wave owns

    f32x4 acc[4][4];
#pragma unroll
    for (int i = 0; i < 4; ++i)
#pragma unroll
        for (int j = 0; j < 4; ++j) acc[i][j] = (f32x4)0.f;

    for (int k0 = 0; k0 < 128; k0 += 32) {
#pragma unroll
        for (int r = 0; r < 2; ++r) {
            int c = t + r * 256;
            int m = c >> 2;
            int row = row0 + m; if (row >= M) row = M - 1;
            const char* ga = (const char*)A + ((size_t)row * 128 + k0) * 2 + (c & 3) * 16;
            gload_lds16(ga, (char*)As + c * 16);
            const char* gb = (const char*)Bt + ((size_t)m * 128 + k0) * 2 + (c & 3) * 16;
            gload_lds16(gb, (char*)Bs + c * 16);
        }
        __syncthreads();

        short8 a[4], b[4];
#pragma unroll
        for (int mi = 0; mi < 4; ++mi)
            a[mi] = *(const short8*)&As[(wm + mi * 16 + cl) * 32 + quad * 8];
#pragma unroll
        for (int ni = 0; ni < 4; ++ni)
            b[ni] = *(const short8*)&Bs[(wn + ni * 16 + cl) * 32 + quad * 8];
#pragma unroll
        for (int mi = 0; mi < 4; ++mi)
#pragma unroll
            for (int ni = 0; ni < 4; ++ni)
                acc[mi][ni] = __builtin_amdgcn_mfma_f32_16x16x32_bf16(a[mi], b[ni], acc[mi][ni], 0, 0, 0);
        __syncthreads();
    }

    // per-column params for this thread's 4 column slots
    float bv[4], gv[4], bev[4];
#pragma unroll
    for (int ni = 0; ni < 4; ++ni) {
        int col = wn + ni * 16 + cl;
        bv[ni] = bias[col]; gv[ni] = gamma[col]; bev[ni] = beta[col];
    }

    // ---- row sums (over this wave's 64 cols) ----
    float s[4][4];
#pragma unroll
    for (int mi = 0; mi < 4; ++mi)
#pragma unroll
        for (int r = 0; r < 4; ++r) {
            float v = (acc[mi][0][r] + bv[0]) + (acc[mi][1][r] + bv[1]) +
                      (acc[mi][2][r] + bv[2]) + (acc[mi][3][r] + bv[3]);
            v += __shfl_xor(v, 1, 64);
            v += __shfl_xor(v, 2, 64);
            v += __shfl_xor(v, 4, 64);
            v += __shfl_xor(v, 8, 64);
            s[mi][r] = v;
        }
    if (cl == 0) {
#pragma unroll
        for (int mi = 0; mi < 4; ++mi)
#pragma unroll
            for (int r = 0; r < 4; ++r)
                redS[wm + mi * 16 + quad * 4 + r][wh] = s[mi][r];
    }
    __syncthreads();
    float mean[4][4];
#pragma unroll
    for (int mi = 0; mi < 4; ++mi)
#pragma unroll
        for (int r = 0; r < 4; ++r) {
            int rl = wm + mi * 16 + quad * 4 + r;
            mean[mi][r] = (redS[rl][0] + redS[rl][1]) * (1.f / 128.f);
        }
    __syncthreads();

    // ---- row variances ----
#pragma unroll
    for (int mi = 0; mi < 4; ++mi)
#pragma unroll
        for (int r = 0; r < 4; ++r) {
            float q = 0.f;
#pragma unroll
            for (int ni = 0; ni < 4; ++ni) {
                float d = acc[mi][ni][r] + bv[ni] - mean[mi][r];
                q = fmaf(d, d, q);
            }
            q += __shfl_xor(q, 1, 64);
            q += __shfl_xor(q, 2, 64);
            q += __shfl_xor(q, 4, 64);
            q += __shfl_xor(q, 8, 64);
            s[mi][r] = q;
        }
    if (cl == 0) {
#pragma unroll
        for (int mi = 0; mi < 4; ++mi)
#pragma unroll
            for (int r = 0; r < 4; ++r)
                redS[wm + mi * 16 + quad * 4 + r][wh] = s[mi][r];
    }
    __syncthreads();

#pragma unroll
    for (int mi = 0; mi < 4; ++mi)
#pragma unroll
        for (int r = 0; r < 4; ++r) {
            int rl = wm + mi * 16 + quad * 4 + r;
            int row = row0 + rl;
            if (row < M) {
                float rstd = rsqrtf((redS[rl][0] + redS[rl][1]) * (1.f / 128.f) + 1e-5f);
#pragma unroll
                for (int ni = 0; ni < 4; ++ni) {
                    int col = wn + ni * 16 + cl;
                    float d = acc[mi][ni][r] + bv[ni] - mean[mi][r];
                    out[(size_t)row * 128 + col] = fmaf(d * rstd, gv[ni], bev[ni]);
                }
            }
        }
}

// ---------------- fused edge-score + softmax aggregate + epilogue ----------------
// ONE WAVE PER DST NODE, nodes handed out DYNAMICALLY from 64 shard counters so
// no wave idles behind a slow sibling (fixes the max-of-4 block-retire imbalance).
// Lane l owns features f0 = 32*(l>>4) + 2*(l&15) and f0+1 (head's 32 channels in
// one 16-lane group -> 4-level shfl head reduce). No LDS, no barriers.
__device__ __forceinline__ void edot16(const float4 E0, const float4 E1,
                                       const float4 E2, const float4 E3,
                                       const float2* __restrict__ w,
                                       float& o0, float& o1) {
    o0 = E0.x * w[0].x;            o1 = E0.x * w[0].y;
    o0 = fmaf(E0.y, w[1].x, o0);   o1 = fmaf(E0.y, w[1].y, o1);
    o0 = fmaf(E0.z, w[2].x, o0);   o1 = fmaf(E0.z, w[2].y, o1);
    o0 = fmaf(E0.w, w[3].x, o0);   o1 = fmaf(E0.w, w[3].y, o1);
    o0 = fmaf(E1.x, w[4].x, o0);   o1 = fmaf(E1.x, w[4].y, o1);
    o0 = fmaf(E1.y, w[5].x, o0);   o1 = fmaf(E1.y, w[5].y, o1);
    o0 = fmaf(E1.z, w[6].x, o0);   o1 = fmaf(E1.z, w[6].y, o1);
    o0 = fmaf(E1.w, w[7].x, o0);   o1 = fmaf(E1.w, w[7].y, o1);
    o0 = fmaf(E2.x, w[8].x, o0);   o1 = fmaf(E2.x, w[8].y, o1);
    o0 = fmaf(E2.y, w[9].x, o0);   o1 = fmaf(E2.y, w[9].y, o1);
    o0 = fmaf(E2.z, w[10].x, o0);  o1 = fmaf(E2.z, w[10].y, o1);
    o0 = fmaf(E2.w, w[11].x, o0);  o1 = fmaf(E2.w, w[11].y, o1);
    o0 = fmaf(E3.x, w[12].x, o0);  o1 = fmaf(E3.x, w[12].y, o1);
    o0 = fmaf(E3.y, w[13].x, o0);  o1 = fmaf(E3.y, w[13].y, o1);
    o0 = fmaf(E3.z, w[14].x, o0);  o1 = fmaf(E3.z, w[14].y, o1);
    o0 = fmaf(E3.w, w[15].x, o0);  o1 = fmaf(E3.w, w[15].y, o1);
}

template <int STRIDE>
__global__ __launch_bounds__(256) void k_fused_agg(const int* __restrict__ off,
                                                   const int2* __restrict__ csr_se,
                                                   const short* __restrict__ C,
                                                   const float* __restrict__ ea,
                                                   const float* __restrict__ We,
                                                   const float* __restrict__ att,
                                                   const short* __restrict__ resid, int rstride,
                                                   const float* __restrict__ bias,
                                                   const float* __restrict__ gamma,
                                                   const float* __restrict__ beta,
                                                   short* __restrict__ outb,
                                                   int* __restrict__ ctr) {
    int t = threadIdx.x;
    int l = t & 63;
    int f0 = (l >> 4) * 32 + (l & 15) * 2;   // even feature; f1 = f0+1 (same head)
    int fp = f0 >> 1;

    float2 wreg[16];
    const float2* We2 = (const float2*)We;
#pragma unroll
    for (int k = 0; k < 16; ++k) wreg[k] = We2[k * 64 + fp];
    float2 av = ((const float2*)att)[fp];
    float2 bs2 = ((const float2*)bias)[fp];
    float2 gv = ((const float2*)gamma)[fp];
    float2 bev = ((const float2*)beta)[fp];

    int shard = blockIdx.x & (NSH - 1);
    int base = shard * SHSZ;
    int* myctr = ctr + shard;

    for (;;) {
        int idx;
        if (l == 0) idx = atomicAdd(myctr, 1);
        idx = __shfl(idx, 0, 64);
        int i = base + idx;
        if (idx >= SHSZ || i >= NN) break;

        unsigned xrp = *(const unsigned*)&C[(size_t)i * STRIDE + 128 + f0];
        float xr0 = bflo(xrp), xr1 = bfhi(xrp);
        unsigned rp = *(const unsigned*)&resid[(size_t)i * rstride + f0];  // early issue

        int b0 = off[i], b1 = off[i + 1];
        float l_run = 0.f, acc0 = 0.f, acc1 = 0.f;
        int pos = b0;
        int2 seA, seB;
        bool have = (pos + 2 <= b1);
        if (have) { seA = csr_se[pos]; seB = csr_se[pos + 1]; }
        while (have) {
            bool haven = (pos + 4 <= b1);
            int2 nA, nB;
            if (haven) { nA = csr_se[pos + 2]; nB = csr_se[pos + 3]; }
            // payload loads for current pair
            const float4* eaA = (const float4*)(ea + (size_t)seA.y * EDIM);
            const float4* eaB = (const float4*)(ea + (size_t)seB.y * EDIM);
            float4 A0 = eaA[0], A1 = eaA[1], A2 = eaA[2], A3 = eaA[3];
            float4 B0 = eaB[0], B1 = eaB[1], B2 = eaB[2], B3 = eaB[3];
            unsigned xlA = *(const unsigned*)&C[(size_t)seA.x * STRIDE + f0];
            unsigned xlB = *(const unsigned*)&C[(size_t)seB.x * STRIDE + f0];
            float eA0, eA1, eB0, eB1;
            edot16(A0, A1, A2, A3, wreg, eA0, eA1);
            edot16(B0, B1, B2, B3, wreg, eB0, eB1);
            float xa0 = bflo(xlA), xa1 = bfhi(xlA);
            float xb0 = bflo(xlB), xb1 = bfhi(xlB);
            float mA0 = xa0 + xr0 + eA0, mA1 = xa1 + xr1 + eA1;
            float mB0 = xb0 + xr0 + eB0, mB1 = xb1 + xr1 + eB1;
            float pA = fmaf(fmaxf(mA1, 0.2f * mA1), av.y, fmaxf(mA0, 0.2f * mA0) * av.x);
            float pB = fmaf(fmaxf(mB1, 0.2f * mB1), av.y, fmaxf(mB0, 0.2f * mB0) * av.x);
            pA += __shfl_xor(pA, 1, 64);  pB += __shfl_xor(pB, 1, 64);
            pA += __shfl_xor(pA, 2, 64);  pB += __shfl_xor(pB, 2, 64);
            pA += __shfl_xor(pA, 4, 64);  pB += __shfl_xor(pB, 4, 64);
            pA += __shfl_xor(pA, 8, 64);  pB += __shfl_xor(pB, 8, 64);
            float peA = __expf(pA), peB = __expf(pB);
            l_run += peA + peB;
            acc0 = fmaf(peA, xa0, acc0); acc1 = fmaf(peA, xa1, acc1);
            acc0 = fmaf(peB, xb0, acc0); acc1 = fmaf(peB, xb1, acc1);
            pos += 2;
            seA = nA; seB = nB;
            have = haven;
        }
        if (pos < b1) {
            int2 se = csr_se[pos];
            const float4* ea4 = (const float4*)(ea + (size_t)se.y * EDIM);
            float4 A0 = ea4[0], A1 = ea4[1], A2 = ea4[2], A3 = ea4[3];
            unsigned xlv = *(const unsigned*)&C[(size_t)se.x * STRIDE + f0];
            float e0, e1;
            edot16(A0, A1, A2, A3, wreg, e0, e1);
            float x0 = bflo(xlv), x1 = bfhi(xlv);
            float m0 = x0 + xr0 + e0, m1 = x1 + xr1 + e1;
            float p = fmaf(fmaxf(m1, 0.2f * m1), av.y, fmaxf(m0, 0.2f * m0) * av.x);
            p += __shfl_xor(p, 1, 64);
            p += __shfl_xor(p, 2, 64);
            p += __shfl_xor(p, 4, 64);
            p += __shfl_xor(p, 8, 64);
            float pe = __expf(p);
            l_run += pe;
            acc0 = fmaf(pe, x0, acc0);
            acc1 = fmaf(pe, x1, acc1);
        }

        float inv = 1.f / (l_run + 1e-16f);
        float o0 = fmaf(acc0, inv, bs2.x);
        float o1 = fmaf(acc1, inv, bs2.y);
        o0 = o0 > 0.f ? o0 : (__expf(o0) - 1.f);            // ELU
        o1 = o1 > 0.f ? o1 : (__expf(o1) - 1.f);
        float v0 = o0 + bflo(rp), v1 = o1 + bfhi(rp);       // + residual
        // in-wave LayerNorm over 128 features (2 per lane)
        float s = v0 + v1;
#pragma unroll
        for (int o = 32; o > 0; o >>= 1) s += __shfl_xor(s, o, 64);
        float mean = s * (1.f / 128.f);
        float d0 = v0 - mean, d1 = v1 - mean;
        float q = fmaf(d0, d0, d1 * d1);
#pragma unroll
        for (int o = 32; o > 0; o >>= 1) q += __shfl_xor(q, o, 64);
        float rstd = rsqrtf(q * (1.f / 128.f) + 1e-5f);
        float r0 = fmaf(d0 * rstd, gv.x, bev.x);
        float r1 = fmaf(d1 * rstd, gv.y, bev.y);
        unsigned op = (unsigned)(unsigned short)f2bf(r0) |
                      (((unsigned)(unsigned short)f2bf(r1)) << 16);
        *(unsigned*)&outb[(size_t)i * 128 + f0] = op;
    }
}

extern "C" void kernel_launch(void* const* d_in, const int* in_sizes, int n_in,
                              void* d_out, int out_size, void* d_ws, size_t ws_size,
                              hipStream_t stream) {
    (void)in_sizes; (void)n_in; (void)out_size; (void)ws_size;
    const float* x     = (const float*)d_in[0];
    const float* ea    = (const float*)d_in[1];
    const float* Wl1   = (const float*)d_in[2];
    const float* bl1   = (const float*)d_in[3];
    const float* Wr1   = (const float*)d_in[4];
    const float* br1   = (const float*)d_in[5];
    const float* We1   = (const float*)d_in[6];
    const float* att1  = (const float*)d_in[7];
    const float* bias1 = (const float*)d_in[8];
    const float* Wl2   = (const float*)d_in[9];
    const float* bl2   = (const float*)d_in[10];
    const float* Wr2   = (const float*)d_in[11];
    const float* br2   = (const float*)d_in[12];
    const float* We2   = (const float*)d_in[13];
    const float* att2  = (const float*)d_in[14];
    const float* bias2 = (const float*)d_in[15];
    const float* Wres  = (const float*)d_in[16];
    const float* bres  = (const float*)d_in[17];
    const float* Wout  = (const float*)d_in[18];
    const float* bout  = (const float*)d_in[19];
    const float* g1    = (const float*)d_in[20];
    const float* bn1   = (const float*)d_in[21];
    const float* g2    = (const float*)d_in[22];
    const float* bn2   = (const float*)d_in[23];
    const float* go    = (const float*)d_in[24];
    const float* bo    = (const float*)d_in[25];
    const int*   ei    = (const int*)d_in[26];
    const int* srcv = ei;
    const int* dstv = ei + NE;
    float* outp = (float*)d_out;

    char* p = (char*)d_ws;
    auto carve = [&](size_t bytes) {
        char* r = p;
        p += (bytes + 255) & ~(size_t)255;
        return r;
    };
    short* xb    = (short*)carve((size_t)NN * KP1 * 2);
    short* Wt1   = (short*)carve((size_t)384 * KP1 * 2);
    short* Wt2   = (short*)carve((size_t)256 * 128 * 2);
    short* Wt3   = (short*)carve((size_t)128 * 128 * 2);
    float* bcat1 = (float*)carve(384 * 4);
    float* bcat2 = (float*)carve(256 * 4);
    short* C1    = (short*)carve((size_t)NN * 384 * 2);   // bf16 [xl|xr|res]
    short* h1b   = (short*)carve((size_t)NN * 128 * 2);
    short* h2b   = (short*)carve((size_t)NN * 128 * 2);
    int* off     = (int*)carve((size_t)(NN + 1) * 4);
    int* cur     = (int*)carve((size_t)NN * 4);
    int* bsum    = (int*)carve(256 * 4);
    int* ctr     = (int*)carve(2 * NSH * 4);              // layer1: [0..63], layer2: [64..127]
    int2* csr_se = (int2*)carve((size_t)NE * 8);

    short* C2 = C1;                                  // stride 256, reuse after layer 1

    const int NB = (NN + 255) / 256;                 // 196

    // ---- CSR build ----
    hipMemsetAsync(cur, 0, (size_t)NN * 4, stream);
    hipMemsetAsync(ctr, 0, 2 * NSH * 4, stream);
    k_count<<<(NE + 255) / 256, 256, 0, stream>>>(dstv, cur);
    k_scan1<<<NB, 256, 0, stream>>>(cur, off, bsum);
    k_scan2<<<1, 256, 0, stream>>>(bsum, NB);
    k_scan3c<<<(NN + 256) / 256, 256, 0, stream>>>(off, bsum, cur);
    k_scatter<<<(NE + 255) / 256, 256, 0, stream>>>(srcv, dstv, cur, csr_se);

    // ---- prep ----
    k_cvt_x<<<((size_t)NN * KP1 + 255) / 256, 256, 0, stream>>>(x, xb);
    int prep_total = 384 * KP1 + 256 * 128 + 128 * 128 + 384 + 256;
    k_prep_w<<<(prep_total + 255) / 256, 256, 0, stream>>>(Wl1, Wr1, Wres, Wl2, Wr2, Wout,
                                                           bl1, br1, bres, bl2, br2,
                                                           Wt1, Wt2, Wt3, bcat1, bcat2);

    int mb = (NN + 127) / 128;                       // 391

    // ---- layer 1 ----
    k_mfma_gemm<true><<<dim3(mb, 3), 256, 0, stream>>>(xb, Wt1, bcat1, nullptr, C1, NN, KP1, 384);
    k_fused_agg<384><<<2048, 256, 0, stream>>>(off, csr_se, C1, ea, We1, att1,
                                               C1 + 256, 384, bias1, g1, bn1, h1b, ctr);
    // ---- layer 2 ----
    k_mfma_gemm<true><<<dim3(mb, 2), 256, 0, stream>>>(h1b, Wt2, bcat2, nullptr, C2, NN, 128, 256);
    k_fused_agg<256><<<2048, 256, 0, stream>>>(off, csr_se, C2, ea, We2, att2,
                                               h1b, 128, bias2, g2, bn2, h2b, ctr + NSH);
    // ---- output: GEMM + fused LN ----
    k_gemm_ln<<<mb, 256, 0, stream>>>(h2b, Wt3, bout, go, bo, outp, NN);
}

// Round 3
// 567.782 us; speedup vs baseline: 1.5203x; 1.5203x over previous
//
#include <hip/hip_runtime.h>
#include <hip/hip_bf16.h>
#include <math.h>
#include <stdint.h>

#define NN 50000
#define NE 500000
#define DIN 264
#define KP1 288      // DIN padded to multiple of 32
#define HID 128
#define EDIM 16

typedef __attribute__((ext_vector_type(8))) short short8;
typedef __attribute__((ext_vector_type(4))) float f32x4;

__device__ __forceinline__ short f2bf(float v) {
    union { float f; unsigned u; } x; x.f = v;
    unsigned r = x.u + 0x7fff + ((x.u >> 16) & 1);
    return (short)(r >> 16);
}
__device__ __forceinline__ float bf2f(short v) {
    union { float f; unsigned u; } x;
    x.u = ((unsigned)(unsigned short)v) << 16;
    return x.f;
}
// unpack two bf16 packed in a dword
__device__ __forceinline__ float bflo(unsigned u) {
    union { float f; unsigned u; } x; x.u = u << 16; return x.f;
}
__device__ __forceinline__ float bfhi(unsigned u) {
    union { float f; unsigned u; } x; x.u = u & 0xffff0000u; return x.f;
}
__device__ __forceinline__ unsigned pk2bf(float a, float b) {
    return (unsigned)(unsigned short)f2bf(a) | ((unsigned)(unsigned short)f2bf(b) << 16);
}

__device__ __forceinline__ void gload_lds16(const void* g, void* l) {
    __builtin_amdgcn_global_load_lds(
        (const __attribute__((address_space(1))) unsigned int*)g,
        (__attribute__((address_space(3))) unsigned int*)l, 16, 0, 0);
}

// ---------------- CSR build (dst -> in-edges) ----------------
__global__ void k_count(const int* __restrict__ dst, int* __restrict__ cnt) {
    int e = blockIdx.x * blockDim.x + threadIdx.x;
    if (e < NE) atomicAdd(&cnt[dst[e]], 1);
}

__global__ __launch_bounds__(256) void k_scan1(const int* __restrict__ cnt,
                                               int* __restrict__ off, int* __restrict__ bsum) {
    __shared__ int buf[256];
    int b = blockIdx.x, t = threadIdx.x;
    int i = b * 256 + t;
    int v = (i < NN) ? cnt[i] : 0;
    buf[t] = v; __syncthreads();
    for (int s = 1; s < 256; s <<= 1) {
        int u = (t >= s) ? buf[t - s] : 0; __syncthreads();
        buf[t] += u; __syncthreads();
    }
    if (i < NN) off[i + 1] = buf[t];
    if (t == 255) bsum[b] = buf[255];
}

__global__ void k_scan2(int* __restrict__ bsum, int nb) {
    __shared__ int buf[256];
    int t = threadIdx.x;
    int o = (t < nb) ? bsum[t] : 0;
    buf[t] = o; __syncthreads();
    for (int s = 1; s < 256; s <<= 1) {
        int u = (t >= s) ? buf[t - s] : 0; __syncthreads();
        buf[t] += u; __syncthreads();
    }
    if (t < nb) bsum[t] = buf[t] - o;   // exclusive
}

// finalize offsets AND copy to cur in one pass
__global__ void k_scan3c(int* __restrict__ off, const int* __restrict__ bsum,
                         int* __restrict__ cur) {
    int j = blockIdx.x * 256 + threadIdx.x;   // 0..NN
    if (j > NN) return;
    int v = (j == 0) ? 0 : off[j] + bsum[(j - 1) >> 8];
    off[j] = v;
    if (j < NN) cur[j] = v;
}

__global__ void k_scatter(const int* __restrict__ src, const int* __restrict__ dst,
                          int* __restrict__ cur, int* __restrict__ srcp,
                          int* __restrict__ ey) {
    int e = blockIdx.x * blockDim.x + threadIdx.x;
    if (e < NE) {
        int d = dst[e];
        int p = atomicAdd(&cur[d], 1);
        srcp[p] = src[e];
        ey[p] = e;
    }
}

// ---------------- weight/bias/input prep ----------------
__global__ void k_cvt_x(const float* __restrict__ x, short* __restrict__ xb) {
    int idx = blockIdx.x * 256 + threadIdx.x;
    if (idx >= NN * KP1) return;
    int i = idx / KP1, k = idx - i * KP1;
    xb[idx] = (k < DIN) ? f2bf(x[(size_t)i * DIN + k]) : (short)0;
}

// all weight transposes + bias concats in ONE dispatch
__global__ void k_prep_w(const float* __restrict__ Wl1, const float* __restrict__ Wr1,
                         const float* __restrict__ Wres, const float* __restrict__ Wl2,
                         const float* __restrict__ Wr2, const float* __restrict__ Wout,
                         const float* __restrict__ bl1, const float* __restrict__ br1,
                         const float* __restrict__ bres, const float* __restrict__ bl2,
                         const float* __restrict__ br2,
                         const float* __restrict__ We1, const float* __restrict__ We2,
                         short* __restrict__ Wt1, short* __restrict__ Wt2,
                         short* __restrict__ Wt3, float* __restrict__ bcat1,
                         float* __restrict__ bcat2,
                         short* __restrict__ WeT1, short* __restrict__ WeT2) {
    int idx = blockIdx.x * 256 + threadIdx.x;
    if (idx < 384 * KP1) {
        int n = idx / KP1, k = idx - n * KP1;
        float v = 0.f;
        if (k < DIN) {
            const float* W = (n < 128) ? Wl1 : ((n < 256) ? Wr1 : Wres);
            v = W[(size_t)k * 128 + (n & 127)];
        }
        Wt1[idx] = f2bf(v);
        return;
    }
    idx -= 384 * KP1;
    if (idx < 256 * 128) {
        int n = idx >> 7, k = idx & 127;
        const float* W = (n < 128) ? Wl2 : Wr2;
        Wt2[idx] = f2bf(W[(size_t)k * 128 + (n & 127)]);
        return;
    }
    idx -= 256 * 128;
    if (idx < 128 * 128) {
        int n = idx >> 7, k = idx & 127;
        Wt3[idx] = f2bf(Wout[(size_t)k * 128 + n]);
        return;
    }
    idx -= 128 * 128;
    if (idx < 384) {
        bcat1[idx] = (idx < 128) ? bl1[idx] : ((idx < 256) ? br1[idx - 128] : bres[idx - 256]);
        return;
    }
    idx -= 384;
    if (idx < 256) {
        bcat2[idx] = (idx < 128) ? bl2[idx] : br2[idx - 128];
        return;
    }
    idx -= 256;
    if (idx < 128 * 32) {
        int n = idx >> 5, k = idx & 31;
        WeT1[idx] = (k < EDIM) ? f2bf(We1[(size_t)k * 128 + n]) : (short)0;
        return;
    }
    idx -= 128 * 32;
    if (idx < 128 * 32) {
        int n = idx >> 5, k = idx & 31;
        WeT2[idx] = (k < EDIM) ? f2bf(We2[(size_t)k * 128 + n]) : (short)0;
    }
}

// gather edge_attr rows into CSR order, f32 -> bf16, K padded 16->32 with zeros
__global__ __launch_bounds__(256) void k_gather_ea(const int* __restrict__ ey,
                                                   const float* __restrict__ ea,
                                                   short* __restrict__ eaperm) {
    int pos = blockIdx.x * 256 + threadIdx.x;
    if (pos >= NE) return;
    int e = ey[pos];
    const float4* r = (const float4*)(ea + (size_t)e * EDIM);
    float4 v0 = r[0], v1 = r[1], v2 = r[2], v3 = r[3];
    uint4 w0 = make_uint4(pk2bf(v0.x, v0.y), pk2bf(v0.z, v0.w),
                          pk2bf(v1.x, v1.y), pk2bf(v1.z, v1.w));
    uint4 w1 = make_uint4(pk2bf(v2.x, v2.y), pk2bf(v2.z, v2.w),
                          pk2bf(v3.x, v3.y), pk2bf(v3.z, v3.w));
    uint4* o = (uint4*)(eaperm + (size_t)pos * 32);
    o[0] = w0; o[1] = w1;
    o[2] = make_uint4(0, 0, 0, 0);
    o[3] = make_uint4(0, 0, 0, 0);
}

// ---------------- bf16 MFMA GEMM: C[M x NS] = A[M x Kpad] @ Bt[NS x Kpad]^T + bias ----------------
template <bool BF16OUT>
__global__ __launch_bounds__(256) void k_mfma_gemm(const short* __restrict__ A,
                                                   const short* __restrict__ Bt,
                                                   const float* __restrict__ bias,
                                                   float* __restrict__ Cf,
                                                   short* __restrict__ Cb,
                                                   int M, int Kpad, int NS) {
    __shared__ short As[128 * 32];
    __shared__ short Bs[128 * 32];
    int t = threadIdx.x;
    int lane = t & 63, wid = t >> 6;
    int wm = (wid & 1) * 64, wn = (wid >> 1) * 64;
    int cl = lane & 15, quad = lane >> 4;
    int row0 = blockIdx.x * 128;
    int col0 = blockIdx.y * 128;

    f32x4 acc[4][4];
#pragma unroll
    for (int i = 0; i < 4; ++i)
#pragma unroll
        for (int j = 0; j < 4; ++j) acc[i][j] = (f32x4)0.f;

    for (int k0 = 0; k0 < Kpad; k0 += 32) {
#pragma unroll
        for (int r = 0; r < 2; ++r) {
            int c = t + r * 256;                     // chunk 0..511
            int m = c >> 2;
            int row = row0 + m; if (row >= M) row = M - 1;
            const char* ga = (const char*)A + ((size_t)row * Kpad + k0) * 2 + (c & 3) * 16;
            gload_lds16(ga, (char*)As + c * 16);
            int n = col0 + m;
            const char* gb = (const char*)Bt + ((size_t)n * Kpad + k0) * 2 + (c & 3) * 16;
            gload_lds16(gb, (char*)Bs + c * 16);
        }
        __syncthreads();

        short8 a[4], b[4];
#pragma unroll
        for (int mi = 0; mi < 4; ++mi)
            a[mi] = *(const short8*)&As[(wm + mi * 16 + cl) * 32 + quad * 8];
#pragma unroll
        for (int ni = 0; ni < 4; ++ni)
            b[ni] = *(const short8*)&Bs[(wn + ni * 16 + cl) * 32 + quad * 8];
#pragma unroll
        for (int mi = 0; mi < 4; ++mi)
#pragma unroll
            for (int ni = 0; ni < 4; ++ni)
                acc[mi][ni] = __builtin_amdgcn_mfma_f32_16x16x32_bf16(a[mi], b[ni], acc[mi][ni], 0, 0, 0);
        __syncthreads();
    }

#pragma unroll
    for (int mi = 0; mi < 4; ++mi)
#pragma unroll
        for (int ni = 0; ni < 4; ++ni) {
            int col = col0 + wn + ni * 16 + cl;
            float bv = bias[col];
#pragma unroll
            for (int r = 0; r < 4; ++r) {
                int row = row0 + wm + mi * 16 + quad * 4 + r;
                if (row < M) {
                    float v = acc[mi][ni][r] + bv;
                    if (BF16OUT) Cb[(size_t)row * NS + col] = f2bf(v);
                    else         Cf[(size_t)row * NS + col] = v;
                }
            }
        }
}

// ---------------- GEMM (M x 128 @ 128x128) with fused LayerNorm epilogue ----------------
__global__ __launch_bounds__(256) void k_gemm_ln(const short* __restrict__ A,
                                                 const short* __restrict__ Bt,
                                                 const float* __restrict__ bias,
                                                 const float* __restrict__ gamma,
                                                 const float* __restrict__ beta,
                                                 float* __restrict__ out, int M) {
    __shared__ short As[128 * 32];
    __shared__ short Bs[128 * 32];
    __shared__ float redS[128][2];
    int t = threadIdx.x;
    int lane = t & 63, wid = t >> 6;
    int wm = (wid & 1) * 64, wn = (wid >> 1) * 64;
    int cl = lane & 15, quad = lane >> 4;
    int row0 = blockIdx.x * 128;
    int wh = wid >> 1;                 // which 64-col half this wave owns

    f32x4 acc[4][4];
#pragma unroll
    for (int i = 0; i < 4; ++i)
#pragma unroll
        for (int j = 0; j < 4; ++j) acc[i][j] = (f32x4)0.f;

    for (int k0 = 0; k0 < 128; k0 += 32) {
#pragma unroll
        for (int r = 0; r < 2; ++r) {
            int c = t + r * 256;
            int m = c >> 2;
            int row = row0 + m; if (row >= M) row = M - 1;
            const char* ga = (const char*)A + ((size_t)row * 128 + k0) * 2 + (c & 3) * 16;
            gload_lds16(ga, (char*)As + c * 16);
            const char* gb = (const char*)Bt + ((size_t)m * 128 + k0) * 2 + (c & 3) * 16;
            gload_lds16(gb, (char*)Bs + c * 16);
        }
        __syncthreads();

        short8 a[4], b[4];
#pragma unroll
        for (int mi = 0; mi < 4; ++mi)
            a[mi] = *(const short8*)&As[(wm + mi * 16 + cl) * 32 + quad * 8];
#pragma unroll
        for (int ni = 0; ni < 4; ++ni)
            b[ni] = *(const short8*)&Bs[(wn + ni * 16 + cl) * 32 + quad * 8];
#pragma unroll
        for (int mi = 0; mi < 4; ++mi)
#pragma unroll
            for (int ni = 0; ni < 4; ++ni)
                acc[mi][ni] = __builtin_amdgcn_mfma_f32_16x16x32_bf16(a[mi], b[ni], acc[mi][ni], 0, 0, 0);
        __syncthreads();
    }

    // per-column params for this thread's 4 column slots
    float bv[4], gv[4], bev[4];
#pragma unroll
    for (int ni = 0; ni < 4; ++ni) {
        int col = wn + ni * 16 + cl;
        bv[ni] = bias[col]; gv[ni] = gamma[col]; bev[ni] = beta[col];
    }

    // ---- row sums (over this wave's 64 cols) ----
    float s[4][4];
#pragma unroll
    for (int mi = 0; mi < 4; ++mi)
#pragma unroll
        for (int r = 0; r < 4; ++r) {
            float v = (acc[mi][0][r] + bv[0]) + (acc[mi][1][r] + bv[1]) +
                      (acc[mi][2][r] + bv[2]) + (acc[mi][3][r] + bv[3]);
            v += __shfl_xor(v, 1, 64);
            v += __shfl_xor(v, 2, 64);
            v += __shfl_xor(v, 4, 64);
            v += __shfl_xor(v, 8, 64);
            s[mi][r] = v;
        }
    if (cl == 0) {
#pragma unroll
        for (int mi = 0; mi < 4; ++mi)
#pragma unroll
            for (int r = 0; r < 4; ++r)
                redS[wm + mi * 16 + quad * 4 + r][wh] = s[mi][r];
    }
    __syncthreads();
    float mean[4][4];
#pragma unroll
    for (int mi = 0; mi < 4; ++mi)
#pragma unroll
        for (int r = 0; r < 4; ++r) {
            int rl = wm + mi * 16 + quad * 4 + r;
            mean[mi][r] = (redS[rl][0] + redS[rl][1]) * (1.f / 128.f);
        }
    __syncthreads();

    // ---- row variances ----
#pragma unroll
    for (int mi = 0; mi < 4; ++mi)
#pragma unroll
        for (int r = 0; r < 4; ++r) {
            float q = 0.f;
#pragma unroll
            for (int ni = 0; ni < 4; ++ni) {
                float d = acc[mi][ni][r] + bv[ni] - mean[mi][r];
                q = fmaf(d, d, q);
            }
            q += __shfl_xor(q, 1, 64);
            q += __shfl_xor(q, 2, 64);
            q += __shfl_xor(q, 4, 64);
            q += __shfl_xor(q, 8, 64);
            s[mi][r] = q;
        }
    if (cl == 0) {
#pragma unroll
        for (int mi = 0; mi < 4; ++mi)
#pragma unroll
            for (int r = 0; r < 4; ++r)
                redS[wm + mi * 16 + quad * 4 + r][wh] = s[mi][r];
    }
    __syncthreads();

#pragma unroll
    for (int mi = 0; mi < 4; ++mi)
#pragma unroll
        for (int r = 0; r < 4; ++r) {
            int rl = wm + mi * 16 + quad * 4 + r;
            int row = row0 + rl;
            if (row < M) {
                float rstd = rsqrtf((redS[rl][0] + redS[rl][1]) * (1.f / 128.f) + 1e-5f);
#pragma unroll
                for (int ni = 0; ni < 4; ++ni) {
                    int col = wn + ni * 16 + cl;
                    float d = acc[mi][ni][r] + bv[ni] - mean[mi][r];
                    out[(size_t)row * 128 + col] = fmaf(d * rstd, gv[ni], bev[ni]);
                }
            }
        }
}

// ---------------- fused edge-score + softmax aggregate + epilogue ----------------
// ONE WAVE PER 4-NODE CONTIGUOUS CHUNK (static; 12500 waves ~5x oversubscribed ->
// HW block scheduler absorbs degree variance; NO atomics). ee = ea@We is
// PRECOMPUTED in CSR order (eep) so the per-edge body is: stream ee dword,
// gather xl dword, add, leaky, att-dot (4-shfl), exp, accumulate.
// Lane l owns features f0 = 32*(l>>4) + 2*(l&15), f0+1 (one head per 16 lanes).
template <int STRIDE>
__global__ __launch_bounds__(256) void k_fused_agg(const int* __restrict__ off,
                                                   const int* __restrict__ srcp,
                                                   const short* __restrict__ eep,
                                                   const short* __restrict__ C,
                                                   const float* __restrict__ att,
                                                   const short* __restrict__ resid, int rstride,
                                                   const float* __restrict__ bias,
                                                   const float* __restrict__ gamma,
                                                   const float* __restrict__ beta,
                                                   short* __restrict__ outb) {
    int t = threadIdx.x;
    int w = t >> 6, l = t & 63;
    int f0 = (l >> 4) * 32 + (l & 15) * 2;   // even feature; f1 = f0+1 (same head)
    int fp = f0 >> 1;

    float2 av = ((const float2*)att)[fp];
    float2 bs2 = ((const float2*)bias)[fp];
    float2 gv = ((const float2*)gamma)[fp];
    float2 bev = ((const float2*)beta)[fp];

    int n0 = (blockIdx.x * 4 + w) * 4;
    int nend = n0 + 4; if (nend > NN) nend = NN;

    for (int i = n0; i < nend; ++i) {
        unsigned xrp = *(const unsigned*)&C[(size_t)i * STRIDE + 128 + f0];
        unsigned rp = *(const unsigned*)&resid[(size_t)i * rstride + f0];  // early issue
        int b0 = off[i], b1 = off[i + 1];
        float xr0 = bflo(xrp), xr1 = bfhi(xrp);

        float l_run = 0.f, acc0 = 0.f, acc1 = 0.f;
        int pos = b0;
        int sA, sB; unsigned eA, eB;
        bool have = (pos + 2 <= b1);
        if (have) {
            sA = srcp[pos]; sB = srcp[pos + 1];
            eA = *(const unsigned*)&eep[(size_t)pos * 128 + f0];
            eB = *(const unsigned*)&eep[(size_t)(pos + 1) * 128 + f0];
        }
        while (have) {
            bool haven = (pos + 4 <= b1);
            int nsA = 0, nsB = 0; unsigned neA = 0, neB = 0;
            if (haven) {
                nsA = srcp[pos + 2]; nsB = srcp[pos + 3];
                neA = *(const unsigned*)&eep[(size_t)(pos + 2) * 128 + f0];
                neB = *(const unsigned*)&eep[(size_t)(pos + 3) * 128 + f0];
            }
            unsigned xlA = *(const unsigned*)&C[(size_t)sA * STRIDE + f0];
            unsigned xlB = *(const unsigned*)&C[(size_t)sB * STRIDE + f0];
            float xa0 = bflo(xlA), xa1 = bfhi(xlA);
            float xb0 = bflo(xlB), xb1 = bfhi(xlB);
            float mA0 = xa0 + xr0 + bflo(eA), mA1 = xa1 + xr1 + bfhi(eA);
            float mB0 = xb0 + xr0 + bflo(eB), mB1 = xb1 + xr1 + bfhi(eB);
            float pA = fmaf(fmaxf(mA1, 0.2f * mA1), av.y, fmaxf(mA0, 0.2f * mA0) * av.x);
            float pB = fmaf(fmaxf(mB1, 0.2f * mB1), av.y, fmaxf(mB0, 0.2f * mB0) * av.x);
            pA += __shfl_xor(pA, 1, 64);  pB += __shfl_xor(pB, 1, 64);
            pA += __shfl_xor(pA, 2, 64);  pB += __shfl_xor(pB, 2, 64);
            pA += __shfl_xor(pA, 4, 64);  pB += __shfl_xor(pB, 4, 64);
            pA += __shfl_xor(pA, 8, 64);  pB += __shfl_xor(pB, 8, 64);
            float peA = __expf(pA), peB = __expf(pB);
            l_run += peA + peB;
            acc0 = fmaf(peA, xa0, acc0); acc1 = fmaf(peA, xa1, acc1);
            acc0 = fmaf(peB, xb0, acc0); acc1 = fmaf(peB, xb1, acc1);
            pos += 2;
            sA = nsA; sB = nsB; eA = neA; eB = neB;
            have = haven;
        }
        if (pos < b1) {
            int s1 = srcp[pos];
            unsigned e1 = *(const unsigned*)&eep[(size_t)pos * 128 + f0];
            unsigned xlv = *(const unsigned*)&C[(size_t)s1 * STRIDE + f0];
            float x0 = bflo(xlv), x1 = bfhi(xlv);
            float m0 = x0 + xr0 + bflo(e1), m1 = x1 + xr1 + bfhi(e1);
            float p = fmaf(fmaxf(m1, 0.2f * m1), av.y, fmaxf(m0, 0.2f * m0) * av.x);
            p += __shfl_xor(p, 1, 64);
            p += __shfl_xor(p, 2, 64);
            p += __shfl_xor(p, 4, 64);
            p += __shfl_xor(p, 8, 64);
            float pe = __expf(p);
            l_run += pe;
            acc0 = fmaf(pe, x0, acc0);
            acc1 = fmaf(pe, x1, acc1);
        }

        float inv = 1.f / (l_run + 1e-16f);
        float o0 = fmaf(acc0, inv, bs2.x);
        float o1 = fmaf(acc1, inv, bs2.y);
        o0 = o0 > 0.f ? o0 : (__expf(o0) - 1.f);            // ELU
        o1 = o1 > 0.f ? o1 : (__expf(o1) - 1.f);
        float v0 = o0 + bflo(rp), v1 = o1 + bfhi(rp);       // + residual
        // in-wave LayerNorm over 128 features (2 per lane)
        float s = v0 + v1;
#pragma unroll
        for (int o = 32; o > 0; o >>= 1) s += __shfl_xor(s, o, 64);
        float mean = s * (1.f / 128.f);
        float d0 = v0 - mean, d1 = v1 - mean;
        float q = fmaf(d0, d0, d1 * d1);
#pragma unroll
        for (int o = 32; o > 0; o >>= 1) q += __shfl_xor(q, o, 64);
        float rstd = rsqrtf(q * (1.f / 128.f) + 1e-5f);
        float r0 = fmaf(d0 * rstd, gv.x, bev.x);
        float r1 = fmaf(d1 * rstd, gv.y, bev.y);
        unsigned op = (unsigned)(unsigned short)f2bf(r0) |
                      (((unsigned)(unsigned short)f2bf(r1)) << 16);
        *(unsigned*)&outb[(size_t)i * 128 + f0] = op;
    }
}

extern "C" void kernel_launch(void* const* d_in, const int* in_sizes, int n_in,
                              void* d_out, int out_size, void* d_ws, size_t ws_size,
                              hipStream_t stream) {
    (void)in_sizes; (void)n_in; (void)out_size; (void)ws_size;
    const float* x     = (const float*)d_in[0];
    const float* ea    = (const float*)d_in[1];
    const float* Wl1   = (const float*)d_in[2];
    const float* bl1   = (const float*)d_in[3];
    const float* Wr1   = (const float*)d_in[4];
    const float* br1   = (const float*)d_in[5];
    const float* We1   = (const float*)d_in[6];
    const float* att1  = (const float*)d_in[7];
    const float* bias1 = (const float*)d_in[8];
    const float* Wl2   = (const float*)d_in[9];
    const float* bl2   = (const float*)d_in[10];
    const float* Wr2   = (const float*)d_in[11];
    const float* br2   = (const float*)d_in[12];
    const float* We2   = (const float*)d_in[13];
    const float* att2  = (const float*)d_in[14];
    const float* bias2 = (const float*)d_in[15];
    const float* Wres  = (const float*)d_in[16];
    const float* bres  = (const float*)d_in[17];
    const float* Wout  = (const float*)d_in[18];
    const float* bout  = (const float*)d_in[19];
    const float* g1    = (const float*)d_in[20];
    const float* bn1   = (const float*)d_in[21];
    const float* g2    = (const float*)d_in[22];
    const float* bn2   = (const float*)d_in[23];
    const float* go    = (const float*)d_in[24];
    const float* bo    = (const float*)d_in[25];
    const int*   ei    = (const int*)d_in[26];
    const int* srcv = ei;
    const int* dstv = ei + NE;
    float* outp = (float*)d_out;

    char* p = (char*)d_ws;
    auto carve = [&](size_t bytes) {
        char* r = p;
        p += (bytes + 255) & ~(size_t)255;
        return r;
    };
    short* xb    = (short*)carve((size_t)NN * KP1 * 2);
    short* Wt1   = (short*)carve((size_t)384 * KP1 * 2);
    short* Wt2   = (short*)carve((size_t)256 * 128 * 2);
    short* Wt3   = (short*)carve((size_t)128 * 128 * 2);
    short* WeT1  = (short*)carve((size_t)128 * 32 * 2);
    short* WeT2  = (short*)carve((size_t)128 * 32 * 2);
    float* bcat1 = (float*)carve(384 * 4);
    float* bcat2 = (float*)carve(256 * 4);
    float* bzero = (float*)carve(128 * 4);
    short* C1    = (short*)carve((size_t)NN * 384 * 2);   // bf16 [xl|xr|res]
    short* h1b   = (short*)carve((size_t)NN * 128 * 2);
    short* h2b   = (short*)carve((size_t)NN * 128 * 2);
    int* off     = (int*)carve((size_t)(NN + 1) * 4);
    int* cur     = (int*)carve((size_t)NN * 4);
    int* bsum    = (int*)carve(256 * 4);
    int* srcp    = (int*)carve((size_t)NE * 4);
    int* ey      = (int*)carve((size_t)NE * 4);
    short* eaperm = (short*)carve((size_t)NE * 32 * 2);   // 32 MB, CSR-ordered bf16 ea (K pad 32)
    short* eep   = (short*)carve((size_t)NE * 128 * 2);   // 128 MB, ee in CSR order (reused both layers)

    short* C2 = C1;                                  // stride 256, reuse after layer 1

    const int NB = (NN + 255) / 256;                 // 196

    // ---- CSR build ----
    hipMemsetAsync(cur, 0, (size_t)NN * 4, stream);
    hipMemsetAsync(bzero, 0, 128 * 4, stream);
    k_count<<<(NE + 255) / 256, 256, 0, stream>>>(dstv, cur);
    k_scan1<<<NB, 256, 0, stream>>>(cur, off, bsum);
    k_scan2<<<1, 256, 0, stream>>>(bsum, NB);
    k_scan3c<<<(NN + 256) / 256, 256, 0, stream>>>(off, bsum, cur);
    k_scatter<<<(NE + 255) / 256, 256, 0, stream>>>(srcv, dstv, cur, srcp, ey);

    // ---- prep ----
    k_cvt_x<<<((size_t)NN * KP1 + 255) / 256, 256, 0, stream>>>(x, xb);
    int prep_total = 384 * KP1 + 256 * 128 + 128 * 128 + 384 + 256 + 2 * 128 * 32;
    k_prep_w<<<(prep_total + 255) / 256, 256, 0, stream>>>(Wl1, Wr1, Wres, Wl2, Wr2, Wout,
                                                           bl1, br1, bres, bl2, br2, We1, We2,
                                                           Wt1, Wt2, Wt3, bcat1, bcat2, WeT1, WeT2);
    k_gather_ea<<<(NE + 255) / 256, 256, 0, stream>>>(ey, ea, eaperm);

    int mb  = (NN + 127) / 128;                      // 391
    int mbe = (NE + 127) / 128;                      // 3907
    int gagg = (NN + 15) / 16;                       // 3125 blocks (4 waves x 4 nodes)

    // ---- layer 1 ----
    k_mfma_gemm<true><<<dim3(mb, 3), 256, 0, stream>>>(xb, Wt1, bcat1, nullptr, C1, NN, KP1, 384);
    k_mfma_gemm<true><<<dim3(mbe, 1), 256, 0, stream>>>(eaperm, WeT1, bzero, nullptr, eep, NE, 32, 128);
    k_fused_agg<384><<<gagg, 256, 0, stream>>>(off, srcp, eep, C1, att1,
                                               C1 + 256, 384, bias1, g1, bn1, h1b);
    // ---- layer 2 ----
    k_mfma_gemm<true><<<dim3(mb, 2), 256, 0, stream>>>(h1b, Wt2, bcat2, nullptr, C2, NN, 128, 256);
    k_mfma_gemm<true><<<dim3(mbe, 1), 256, 0, stream>>>(eaperm, WeT2, bzero, nullptr, eep, NE, 32, 128);
    k_fused_agg<256><<<gagg, 256, 0, stream>>>(off, srcp, eep, C2, att2,
                                               h1b, 128, bias2, g2, bn2, h2b);
    // ---- output: GEMM + fused LN ----
    k_gemm_ln<<<mb, 256, 0, stream>>>(h2b, Wt3, bout, go, bo, outp, NN);
}

// Round 4
// 508.712 us; speedup vs baseline: 1.6968x; 1.1161x over previous
//
#include <hip/hip_runtime.h>
#include <hip/hip_bf16.h>
#include <math.h>
#include <stdint.h>

#define NN 50000
#define NE 500000
#define DIN 264
#define KP1 288      // DIN padded to multiple of 32
#define HID 128
#define EDIM 16
#define GS_LD 136    // LDS row stride (shorts) for g-matrix: 16B-aligned, bank-spread

typedef __attribute__((ext_vector_type(8))) short short8;
typedef __attribute__((ext_vector_type(4))) float f32x4;

__device__ __forceinline__ short f2bf(float v) {
    union { float f; unsigned u; } x; x.f = v;
    unsigned r = x.u + 0x7fff + ((x.u >> 16) & 1);
    return (short)(r >> 16);
}
__device__ __forceinline__ float bf2f(short v) {
    union { float f; unsigned u; } x;
    x.u = ((unsigned)(unsigned short)v) << 16;
    return x.f;
}
// unpack two bf16 packed in a dword
__device__ __forceinline__ float bflo(unsigned u) {
    union { float f; unsigned u; } x; x.u = u << 16; return x.f;
}
__device__ __forceinline__ float bfhi(unsigned u) {
    union { float f; unsigned u; } x; x.u = u & 0xffff0000u; return x.f;
}
__device__ __forceinline__ unsigned pk2bf(float a, float b) {
    return (unsigned)(unsigned short)f2bf(a) | ((unsigned)(unsigned short)f2bf(b) << 16);
}

__device__ __forceinline__ void gload_lds16(const void* g, void* l) {
    __builtin_amdgcn_global_load_lds(
        (const __attribute__((address_space(1))) unsigned int*)g,
        (__attribute__((address_space(3))) unsigned int*)l, 16, 0, 0);
}

// ---------------- CSR build (dst -> in-edges) ----------------
__global__ void k_count(const int* __restrict__ dst, int* __restrict__ cnt) {
    int e = blockIdx.x * blockDim.x + threadIdx.x;
    if (e < NE) atomicAdd(&cnt[dst[e]], 1);
}

__global__ __launch_bounds__(256) void k_scan1(const int* __restrict__ cnt,
                                               int* __restrict__ off, int* __restrict__ bsum) {
    __shared__ int buf[256];
    int b = blockIdx.x, t = threadIdx.x;
    int i = b * 256 + t;
    int v = (i < NN) ? cnt[i] : 0;
    buf[t] = v; __syncthreads();
    for (int s = 1; s < 256; s <<= 1) {
        int u = (t >= s) ? buf[t - s] : 0; __syncthreads();
        buf[t] += u; __syncthreads();
    }
    if (i < NN) off[i + 1] = buf[t];
    if (t == 255) bsum[b] = buf[255];
}

__global__ void k_scan2(int* __restrict__ bsum, int nb) {
    __shared__ int buf[256];
    int t = threadIdx.x;
    int o = (t < nb) ? bsum[t] : 0;
    buf[t] = o; __syncthreads();
    for (int s = 1; s < 256; s <<= 1) {
        int u = (t >= s) ? buf[t - s] : 0; __syncthreads();
        buf[t] += u; __syncthreads();
    }
    if (t < nb) bsum[t] = buf[t] - o;   // exclusive
}

// finalize offsets AND copy to cur in one pass
__global__ void k_scan3c(int* __restrict__ off, const int* __restrict__ bsum,
                         int* __restrict__ cur) {
    int j = blockIdx.x * 256 + threadIdx.x;   // 0..NN
    if (j > NN) return;
    int v = (j == 0) ? 0 : off[j] + bsum[(j - 1) >> 8];
    off[j] = v;
    if (j < NN) cur[j] = v;
}

__global__ void k_scatter(const int* __restrict__ src, const int* __restrict__ dst,
                          int* __restrict__ cur, int* __restrict__ srcp,
                          int* __restrict__ dstp, int* __restrict__ ey) {
    int e = blockIdx.x * blockDim.x + threadIdx.x;
    if (e < NE) {
        int d = dst[e];
        int p = atomicAdd(&cur[d], 1);
        srcp[p] = src[e];
        dstp[p] = d;
        ey[p] = e;
    }
}

// ---------------- weight/bias/input prep ----------------
__global__ void k_cvt_x(const float* __restrict__ x, short* __restrict__ xb) {
    int idx = blockIdx.x * 256 + threadIdx.x;
    if (idx >= NN * KP1) return;
    int i = idx / KP1, k = idx - i * KP1;
    xb[idx] = (k < DIN) ? f2bf(x[(size_t)i * DIN + k]) : (short)0;
}

// all weight transposes + bias concats + att block-diag expansion in ONE dispatch
__global__ void k_prep_w(const float* __restrict__ Wl1, const float* __restrict__ Wr1,
                         const float* __restrict__ Wres, const float* __restrict__ Wl2,
                         const float* __restrict__ Wr2, const float* __restrict__ Wout,
                         const float* __restrict__ bl1, const float* __restrict__ br1,
                         const float* __restrict__ bres, const float* __restrict__ bl2,
                         const float* __restrict__ br2,
                         const float* __restrict__ We1, const float* __restrict__ We2,
                         const float* __restrict__ att1, const float* __restrict__ att2,
                         short* __restrict__ Wt1, short* __restrict__ Wt2,
                         short* __restrict__ Wt3, float* __restrict__ bcat1,
                         float* __restrict__ bcat2,
                         short* __restrict__ WeT1, short* __restrict__ WeT2,
                         short* __restrict__ attB1, short* __restrict__ attB2) {
    int idx = blockIdx.x * 256 + threadIdx.x;
    if (idx < 384 * KP1) {
        int n = idx / KP1, k = idx - n * KP1;
        float v = 0.f;
        if (k < DIN) {
            const float* W = (n < 128) ? Wl1 : ((n < 256) ? Wr1 : Wres);
            v = W[(size_t)k * 128 + (n & 127)];
        }
        Wt1[idx] = f2bf(v);
        return;
    }
    idx -= 384 * KP1;
    if (idx < 256 * 128) {
        int n = idx >> 7, k = idx & 127;
        const float* W = (n < 128) ? Wl2 : Wr2;
        Wt2[idx] = f2bf(W[(size_t)k * 128 + (n & 127)]);
        return;
    }
    idx -= 256 * 128;
    if (idx < 128 * 128) {
        int n = idx >> 7, k = idx & 127;
        Wt3[idx] = f2bf(Wout[(size_t)k * 128 + n]);
        return;
    }
    idx -= 128 * 128;
    if (idx < 384) {
        bcat1[idx] = (idx < 128) ? bl1[idx] : ((idx < 256) ? br1[idx - 128] : bres[idx - 256]);
        return;
    }
    idx -= 384;
    if (idx < 256) {
        bcat2[idx] = (idx < 128) ? bl2[idx] : br2[idx - 128];
        return;
    }
    idx -= 256;
    if (idx < 128 * 32) {
        int n = idx >> 5, k = idx & 31;
        WeT1[idx] = (k < EDIM) ? f2bf(We1[(size_t)k * 128 + n]) : (short)0;
        return;
    }
    idx -= 128 * 32;
    if (idx < 128 * 32) {
        int n = idx >> 5, k = idx & 31;
        WeT2[idx] = (k < EDIM) ? f2bf(We2[(size_t)k * 128 + n]) : (short)0;
        return;
    }
    idx -= 128 * 32;
    if (idx < 16 * 128) {
        int n = idx >> 7, k = idx & 127;
        attB1[idx] = (n == (k >> 5)) ? f2bf(att1[k]) : (short)0;
        return;
    }
    idx -= 16 * 128;
    if (idx < 16 * 128) {
        int n = idx >> 7, k = idx & 127;
        attB2[idx] = (n == (k >> 5)) ? f2bf(att2[k]) : (short)0;
    }
}

// gather edge_attr rows into CSR order, f32 -> bf16, K padded 16->32 with zeros
__global__ __launch_bounds__(256) void k_gather_ea(const int* __restrict__ ey,
                                                   const float* __restrict__ ea,
                                                   short* __restrict__ eaperm) {
    int pos = blockIdx.x * 256 + threadIdx.x;
    if (pos >= NE) return;
    int e = ey[pos];
    const float4* r = (const float4*)(ea + (size_t)e * EDIM);
    float4 v0 = r[0], v1 = r[1], v2 = r[2], v3 = r[3];
    uint4 w0 = make_uint4(pk2bf(v0.x, v0.y), pk2bf(v0.z, v0.w),
                          pk2bf(v1.x, v1.y), pk2bf(v1.z, v1.w));
    uint4 w1 = make_uint4(pk2bf(v2.x, v2.y), pk2bf(v2.z, v2.w),
                          pk2bf(v3.x, v3.y), pk2bf(v3.z, v3.w));
    uint4* o = (uint4*)(eaperm + (size_t)pos * 32);
    o[0] = w0; o[1] = w1;
    o[2] = make_uint4(0, 0, 0, 0);
    o[3] = make_uint4(0, 0, 0, 0);
}

// ---------------- bf16 MFMA GEMM: C[M x NS] = A[M x Kpad] @ Bt[NS x Kpad]^T + bias ----------------
template <bool BF16OUT>
__global__ __launch_bounds__(256) void k_mfma_gemm(const short* __restrict__ A,
                                                   const short* __restrict__ Bt,
                                                   const float* __restrict__ bias,
                                                   float* __restrict__ Cf,
                                                   short* __restrict__ Cb,
                                                   int M, int Kpad, int NS) {
    __shared__ short As[128 * 32];
    __shared__ short Bs[128 * 32];
    int t = threadIdx.x;
    int lane = t & 63, wid = t >> 6;
    int wm = (wid & 1) * 64, wn = (wid >> 1) * 64;
    int cl = lane & 15, quad = lane >> 4;
    int row0 = blockIdx.x * 128;
    int col0 = blockIdx.y * 128;

    f32x4 acc[4][4];
#pragma unroll
    for (int i = 0; i < 4; ++i)
#pragma unroll
        for (int j = 0; j < 4; ++j) acc[i][j] = (f32x4)0.f;

    for (int k0 = 0; k0 < Kpad; k0 += 32) {
#pragma unroll
        for (int r = 0; r < 2; ++r) {
            int c = t + r * 256;                     // chunk 0..511
            int m = c >> 2;
            int row = row0 + m; if (row >= M) row = M - 1;
            const char* ga = (const char*)A + ((size_t)row * Kpad + k0) * 2 + (c & 3) * 16;
            gload_lds16(ga, (char*)As + c * 16);
            int n = col0 + m;
            const char* gb = (const char*)Bt + ((size_t)n * Kpad + k0) * 2 + (c & 3) * 16;
            gload_lds16(gb, (char*)Bs + c * 16);
        }
        __syncthreads();

        short8 a[4], b[4];
#pragma unroll
        for (int mi = 0; mi < 4; ++mi)
            a[mi] = *(const short8*)&As[(wm + mi * 16 + cl) * 32 + quad * 8];
#pragma unroll
        for (int ni = 0; ni < 4; ++ni)
            b[ni] = *(const short8*)&Bs[(wn + ni * 16 + cl) * 32 + quad * 8];
#pragma unroll
        for (int mi = 0; mi < 4; ++mi)
#pragma unroll
            for (int ni = 0; ni < 4; ++ni)
                acc[mi][ni] = __builtin_amdgcn_mfma_f32_16x16x32_bf16(a[mi], b[ni], acc[mi][ni], 0, 0, 0);
        __syncthreads();
    }

#pragma unroll
    for (int mi = 0; mi < 4; ++mi)
#pragma unroll
        for (int ni = 0; ni < 4; ++ni) {
            int col = col0 + wn + ni * 16 + cl;
            float bv = bias[col];
#pragma unroll
            for (int r = 0; r < 4; ++r) {
                int row = row0 + wm + mi * 16 + quad * 4 + r;
                if (row < M) {
                    float v = acc[mi][ni][r] + bv;
                    if (BF16OUT) Cb[(size_t)row * NS + col] = f2bf(v);
                    else         Cf[(size_t)row * NS + col] = v;
                }
            }
        }
}

// ---------------- GEMM (M x 128 @ 128x128) with fused LayerNorm epilogue ----------------
__global__ __launch_bounds__(256) void k_gemm_ln(const short* __restrict__ A,
                                                 const short* __restrict__ Bt,
                                                 const float* __restrict__ bias,
                                                 const float* __restrict__ gamma,
                                                 const float* __restrict__ beta,
                                                 float* __restrict__ out, int M) {
    __shared__ short As[128 * 32];
    __shared__ short Bs[128 * 32];
    __shared__ float redS[128][2];
    int t = threadIdx.x;
    int lane = t & 63, wid = t >> 6;
    int wm = (wid & 1) * 64, wn = (wid >> 1) * 64;
    int cl = lane & 15, quad = lane >> 4;
    int row0 = blockIdx.x * 128;
    int wh = wid >> 1;                 // which 64-col half this wave owns

    f32x4 acc[4][4];
#pragma unroll
    for (int i = 0; i < 4; ++i)
#pragma unroll
        for (int j = 0; j < 4; ++j) acc[i][j] = (f32x4)0.f;

    for (int k0 = 0; k0 < 128; k0 += 32) {
#pragma unroll
        for (int r = 0; r < 2; ++r) {
            int c = t + r * 256;
            int m = c >> 2;
            int row = row0 + m; if (row >= M) row = M - 1;
            const char* ga = (const char*)A + ((size_t)row * 128 + k0) * 2 + (c & 3) * 16;
            gload_lds16(ga, (char*)As + c * 16);
            const char* gb = (const char*)Bt + ((size_t)m * 128 + k0) * 2 + (c & 3) * 16;
            gload_lds16(gb, (char*)Bs + c * 16);
        }
        __syncthreads();

        short8 a[4], b[4];
#pragma unroll
        for (int mi = 0; mi < 4; ++mi)
            a[mi] = *(const short8*)&As[(wm + mi * 16 + cl) * 32 + quad * 8];
#pragma unroll
        for (int ni = 0; ni < 4; ++ni)
            b[ni] = *(const short8*)&Bs[(wn + ni * 16 + cl) * 32 + quad * 8];
#pragma unroll
        for (int mi = 0; mi < 4; ++mi)
#pragma unroll
            for (int ni = 0; ni < 4; ++ni)
                acc[mi][ni] = __builtin_amdgcn_mfma_f32_16x16x32_bf16(a[mi], b[ni], acc[mi][ni], 0, 0, 0);
        __syncthreads();
    }

    // per-column params for this thread's 4 column slots
    float bv[4], gv[4], bev[4];
#pragma unroll
    for (int ni = 0; ni < 4; ++ni) {
        int col = wn + ni * 16 + cl;
        bv[ni] = bias[col]; gv[ni] = gamma[col]; bev[ni] = beta[col];
    }

    // ---- row sums (over this wave's 64 cols) ----
    float s[4][4];
#pragma unroll
    for (int mi = 0; mi < 4; ++mi)
#pragma unroll
        for (int r = 0; r < 4; ++r) {
            float v = (acc[mi][0][r] + bv[0]) + (acc[mi][1][r] + bv[1]) +
                      (acc[mi][2][r] + bv[2]) + (acc[mi][3][r] + bv[3]);
            v += __shfl_xor(v, 1, 64);
            v += __shfl_xor(v, 2, 64);
            v += __shfl_xor(v, 4, 64);
            v += __shfl_xor(v, 8, 64);
            s[mi][r] = v;
        }
    if (cl == 0) {
#pragma unroll
        for (int mi = 0; mi < 4; ++mi)
#pragma unroll
            for (int r = 0; r < 4; ++r)
                redS[wm + mi * 16 + quad * 4 + r][wh] = s[mi][r];
    }
    __syncthreads();
    float mean[4][4];
#pragma unroll
    for (int mi = 0; mi < 4; ++mi)
#pragma unroll
        for (int r = 0; r < 4; ++r) {
            int rl = wm + mi * 16 + quad * 4 + r;
            mean[mi][r] = (redS[rl][0] + redS[rl][1]) * (1.f / 128.f);
        }
    __syncthreads();

    // ---- row variances ----
#pragma unroll
    for (int mi = 0; mi < 4; ++mi)
#pragma unroll
        for (int r = 0; r < 4; ++r) {
            float q = 0.f;
#pragma unroll
            for (int ni = 0; ni < 4; ++ni) {
                float d = acc[mi][ni][r] + bv[ni] - mean[mi][r];
                q = fmaf(d, d, q);
            }
            q += __shfl_xor(q, 1, 64);
            q += __shfl_xor(q, 2, 64);
            q += __shfl_xor(q, 4, 64);
            q += __shfl_xor(q, 8, 64);
            s[mi][r] = q;
        }
    if (cl == 0) {
#pragma unroll
        for (int mi = 0; mi < 4; ++mi)
#pragma unroll
            for (int r = 0; r < 4; ++r)
                redS[wm + mi * 16 + quad * 4 + r][wh] = s[mi][r];
    }
    __syncthreads();

#pragma unroll
    for (int mi = 0; mi < 4; ++mi)
#pragma unroll
        for (int r = 0; r < 4; ++r) {
            int rl = wm + mi * 16 + quad * 4 + r;
            int row = row0 + rl;
            if (row < M) {
                float rstd = rsqrtf((redS[rl][0] + redS[rl][1]) * (1.f / 128.f) + 1e-5f);
#pragma unroll
                for (int ni = 0; ni < 4; ++ni) {
                    int col = wn + ni * 16 + cl;
                    float d = acc[mi][ni][r] + bv[ni] - mean[mi][r];
                    out[(size_t)row * 128 + col] = fmaf(d * rstd, gv[ni], bev[ni]);
                }
            }
        }
}

// ---------------- edge score kernel ----------------
// Per block: 128 CSR-ordered edges.
// Phase 1: ee[128x128] = eaperm_tile @ WeT (MFMA, K=32).
// Phase 2: g = leaky(ee + xl[src] + xr[dst]) elementwise -> LDS (bf16).
// Phase 3: S[128x16] = g @ attB^T (MFMA, K=128; attB block-diag, 4 live cols).
// Phase 4: pe[pos,h] = exp(S).  The 128-wide edge vector never leaves the block.
template <int STRIDE>
__global__ __launch_bounds__(256) void k_edge_score(const short* __restrict__ eaperm,
                                                    const short* __restrict__ WeT,
                                                    const short* __restrict__ attB,
                                                    const int* __restrict__ srcp,
                                                    const int* __restrict__ dstp,
                                                    const short* __restrict__ C,
                                                    float* __restrict__ pe) {
    __shared__ short As[128 * 32];
    __shared__ short Bs[128 * 32];
    __shared__ short Gs[128 * GS_LD];
    __shared__ short Ab[16 * 128];
    __shared__ int sS[128], sD[128];
    int t = threadIdx.x;
    int lane = t & 63, wid = t >> 6;
    int wm = (wid & 1) * 64, wn = (wid >> 1) * 64;
    int cl = lane & 15, quad = lane >> 4;
    long e0 = (long)blockIdx.x * 128;

    if (t < 128) {
        long ep = e0 + t; if (ep >= NE) ep = NE - 1;
        sS[t] = srcp[ep];
        sD[t] = dstp[ep];
    }
    ((uint4*)Ab)[t] = ((const uint4*)attB)[t];      // 256 x 16B = 4 KB

#pragma unroll
    for (int r = 0; r < 2; ++r) {
        int c = t + r * 256;                        // 512 chunks of 16B
        int m = c >> 2;
        long row = e0 + m; if (row >= NE) row = NE - 1;
        const char* ga = (const char*)eaperm + row * 64 + (c & 3) * 16;
        gload_lds16(ga, (char*)As + c * 16);
        const char* gb = (const char*)WeT + (size_t)m * 64 + (c & 3) * 16;
        gload_lds16(gb, (char*)Bs + c * 16);
    }
    __syncthreads();

    // ---- phase 1: ee GEMM ----
    f32x4 acc[4][4];
#pragma unroll
    for (int i = 0; i < 4; ++i)
#pragma unroll
        for (int j = 0; j < 4; ++j) acc[i][j] = (f32x4)0.f;
    {
        short8 a[4], b[4];
#pragma unroll
        for (int mi = 0; mi < 4; ++mi)
            a[mi] = *(const short8*)&As[(wm + mi * 16 + cl) * 32 + quad * 8];
#pragma unroll
        for (int ni = 0; ni < 4; ++ni)
            b[ni] = *(const short8*)&Bs[(wn + ni * 16 + cl) * 32 + quad * 8];
#pragma unroll
        for (int mi = 0; mi < 4; ++mi)
#pragma unroll
            for (int ni = 0; ni < 4; ++ni)
                acc[mi][ni] = __builtin_amdgcn_mfma_f32_16x16x32_bf16(a[mi], b[ni], acc[mi][ni], 0, 0, 0);
    }

    // ---- phase 2: g = leaky(ee + xl + xr) -> Gs ----
#pragma unroll
    for (int mi = 0; mi < 4; ++mi) {
#pragma unroll
        for (int r = 0; r < 4; ++r) {
            int eloc = wm + mi * 16 + quad * 4 + r;
            const short* xlr = C + (size_t)sS[eloc] * STRIDE;
            const short* xrr = C + (size_t)sD[eloc] * STRIDE + 128;
#pragma unroll
            for (int ni = 0; ni < 4; ++ni) {
                int f = wn + ni * 16 + cl;
                float g = acc[mi][ni][r] + bf2f(xlr[f]) + bf2f(xrr[f]);
                g = fmaxf(g, 0.2f * g);
                Gs[eloc * GS_LD + f] = f2bf(g);
            }
        }
    }
    __syncthreads();

    // ---- phase 3: scores = g @ attB^T ----
    f32x4 sacc[2];
    sacc[0] = (f32x4)0.f; sacc[1] = (f32x4)0.f;
    int em0 = wid * 32;
#pragma unroll
    for (int mt = 0; mt < 2; ++mt) {
#pragma unroll
        for (int ks = 0; ks < 4; ++ks) {
            short8 ag = *(const short8*)&Gs[(em0 + mt * 16 + cl) * GS_LD + ks * 32 + quad * 8];
            short8 bg = *(const short8*)&Ab[cl * 128 + ks * 32 + quad * 8];
            sacc[mt] = __builtin_amdgcn_mfma_f32_16x16x32_bf16(ag, bg, sacc[mt], 0, 0, 0);
        }
    }

    // ---- phase 4: exp + store (C layout: col=lane&15, row=quad*4+r) ----
    if (cl < 4) {
#pragma unroll
        for (int mt = 0; mt < 2; ++mt) {
#pragma unroll
            for (int r = 0; r < 4; ++r) {
                long epos = e0 + em0 + mt * 16 + quad * 4 + r;
                if (epos < NE) pe[epos * 4 + cl] = __expf(sacc[mt][r]);
            }
        }
    }
}

// ---------------- slim softmax-aggregate + epilogue ----------------
// ONE WAVE PER 4-NODE CHUNK. Per edge: srcp + pe (per-head broadcast) + xl dword
// + 3 FMAs. No shfl, no exp (scores precomputed by k_edge_score). l_run needs no
// reduce: pe is uniform across each 16-lane head group. Two accumulator sets
// break the serial FMA chain; next-pair prefetch hides gather latency.
template <int STRIDE>
__global__ __launch_bounds__(256) void k_fused_agg(const int* __restrict__ off,
                                                   const int* __restrict__ srcp,
                                                   const float* __restrict__ pe,
                                                   const short* __restrict__ C,
                                                   const short* __restrict__ resid, int rstride,
                                                   const float* __restrict__ bias,
                                                   const float* __restrict__ gamma,
                                                   const float* __restrict__ beta,
                                                   short* __restrict__ outb) {
    int t = threadIdx.x;
    int w = t >> 6, l = t & 63;
    int f0 = (l >> 4) * 32 + (l & 15) * 2;   // even feature; f1 = f0+1 (same head)
    int fp = f0 >> 1;
    int hd = l >> 4;                          // head index

    float2 bs2 = ((const float2*)bias)[fp];
    float2 gv = ((const float2*)gamma)[fp];
    float2 bev = ((const float2*)beta)[fp];

    int n0 = (blockIdx.x * 4 + w) * 4;
    int nend = n0 + 4; if (nend > NN) nend = NN;

    for (int i = n0; i < nend; ++i) {
        unsigned rp = *(const unsigned*)&resid[(size_t)i * rstride + f0];  // early issue
        int b0 = off[i], b1 = off[i + 1];

        float lA = 0.f, aA0 = 0.f, aA1 = 0.f;
        float lB = 0.f, aB0 = 0.f, aB1 = 0.f;
        int pos = b0;
        int sA = 0, sB = 0; float pA = 0.f, pB = 0.f;
        bool have = (pos + 2 <= b1);
        if (have) {
            sA = srcp[pos]; sB = srcp[pos + 1];
            pA = pe[(size_t)pos * 4 + hd]; pB = pe[(size_t)(pos + 1) * 4 + hd];
        }
        while (have) {
            bool haven = (pos + 4 <= b1);
            int nsA = 0, nsB = 0; float npA = 0.f, npB = 0.f;
            if (haven) {
                nsA = srcp[pos + 2]; nsB = srcp[pos + 3];
                npA = pe[(size_t)(pos + 2) * 4 + hd]; npB = pe[(size_t)(pos + 3) * 4 + hd];
            }
            unsigned xlA = *(const unsigned*)&C[(size_t)sA * STRIDE + f0];
            unsigned xlB = *(const unsigned*)&C[(size_t)sB * STRIDE + f0];
            lA += pA; lB += pB;
            aA0 = fmaf(pA, bflo(xlA), aA0);
            aA1 = fmaf(pA, bfhi(xlA), aA1);
            aB0 = fmaf(pB, bflo(xlB), aB0);
            aB1 = fmaf(pB, bfhi(xlB), aB1);
            pos += 2;
            sA = nsA; sB = nsB; pA = npA; pB = npB;
            have = haven;
        }
        if (pos < b1) {
            int s1 = srcp[pos];
            float p1 = pe[(size_t)pos * 4 + hd];
            unsigned xlv = *(const unsigned*)&C[(size_t)s1 * STRIDE + f0];
            lA += p1;
            aA0 = fmaf(p1, bflo(xlv), aA0);
            aA1 = fmaf(p1, bfhi(xlv), aA1);
        }
        float l_run = lA + lB;
        float acc0 = aA0 + aB0, acc1 = aA1 + aB1;

        float inv = 1.f / (l_run + 1e-16f);
        float o0 = fmaf(acc0, inv, bs2.x);
        float o1 = fmaf(acc1, inv, bs2.y);
        o0 = o0 > 0.f ? o0 : (__expf(o0) - 1.f);            // ELU
        o1 = o1 > 0.f ? o1 : (__expf(o1) - 1.f);
        float v0 = o0 + bflo(rp), v1 = o1 + bfhi(rp);       // + residual
        // in-wave LayerNorm over 128 features (2 per lane)
        float s = v0 + v1;
#pragma unroll
        for (int o = 32; o > 0; o >>= 1) s += __shfl_xor(s, o, 64);
        float mean = s * (1.f / 128.f);
        float d0 = v0 - mean, d1 = v1 - mean;
        float q = fmaf(d0, d0, d1 * d1);
#pragma unroll
        for (int o = 32; o > 0; o >>= 1) q += __shfl_xor(q, o, 64);
        float rstd = rsqrtf(q * (1.f / 128.f) + 1e-5f);
        float r0 = fmaf(d0 * rstd, gv.x, bev.x);
        float r1 = fmaf(d1 * rstd, gv.y, bev.y);
        unsigned op = (unsigned)(unsigned short)f2bf(r0) |
                      (((unsigned)(unsigned short)f2bf(r1)) << 16);
        *(unsigned*)&outb[(size_t)i * 128 + f0] = op;
    }
}

extern "C" void kernel_launch(void* const* d_in, const int* in_sizes, int n_in,
                              void* d_out, int out_size, void* d_ws, size_t ws_size,
                              hipStream_t stream) {
    (void)in_sizes; (void)n_in; (void)out_size; (void)ws_size;
    const float* x     = (const float*)d_in[0];
    const float* ea    = (const float*)d_in[1];
    const float* Wl1   = (const float*)d_in[2];
    const float* bl1   = (const float*)d_in[3];
    const float* Wr1   = (const float*)d_in[4];
    const float* br1   = (const float*)d_in[5];
    const float* We1   = (const float*)d_in[6];
    const float* att1  = (const float*)d_in[7];
    const float* bias1 = (const float*)d_in[8];
    const float* Wl2   = (const float*)d_in[9];
    const float* bl2   = (const float*)d_in[10];
    const float* Wr2   = (const float*)d_in[11];
    const float* br2   = (const float*)d_in[12];
    const float* We2   = (const float*)d_in[13];
    const float* att2  = (const float*)d_in[14];
    const float* bias2 = (const float*)d_in[15];
    const float* Wres  = (const float*)d_in[16];
    const float* bres  = (const float*)d_in[17];
    const float* Wout  = (const float*)d_in[18];
    const float* bout  = (const float*)d_in[19];
    const float* g1    = (const float*)d_in[20];
    const float* bn1   = (const float*)d_in[21];
    const float* g2    = (const float*)d_in[22];
    const float* bn2   = (const float*)d_in[23];
    const float* go    = (const float*)d_in[24];
    const float* bo    = (const float*)d_in[25];
    const int*   ei    = (const int*)d_in[26];
    const int* srcv = ei;
    const int* dstv = ei + NE;
    float* outp = (float*)d_out;

    char* p = (char*)d_ws;
    auto carve = [&](size_t bytes) {
        char* r = p;
        p += (bytes + 255) & ~(size_t)255;
        return r;
    };
    short* xb    = (short*)carve((size_t)NN * KP1 * 2);
    short* Wt1   = (short*)carve((size_t)384 * KP1 * 2);
    short* Wt2   = (short*)carve((size_t)256 * 128 * 2);
    short* Wt3   = (short*)carve((size_t)128 * 128 * 2);
    short* WeT1  = (short*)carve((size_t)128 * 32 * 2);
    short* WeT2  = (short*)carve((size_t)128 * 32 * 2);
    short* attB1 = (short*)carve((size_t)16 * 128 * 2);
    short* attB2 = (short*)carve((size_t)16 * 128 * 2);
    float* bcat1 = (float*)carve(384 * 4);
    float* bcat2 = (float*)carve(256 * 4);
    short* C1    = (short*)carve((size_t)NN * 384 * 2);   // bf16 [xl|xr|res]
    short* h1b   = (short*)carve((size_t)NN * 128 * 2);
    short* h2b   = (short*)carve((size_t)NN * 128 * 2);
    int* off     = (int*)carve((size_t)(NN + 1) * 4);
    int* cur     = (int*)carve((size_t)NN * 4);
    int* bsum    = (int*)carve(256 * 4);
    int* srcp    = (int*)carve((size_t)NE * 4);
    int* dstp    = (int*)carve((size_t)NE * 4);
    int* ey      = (int*)carve((size_t)NE * 4);
    short* eaperm = (short*)carve((size_t)NE * 32 * 2);   // 32 MB, CSR-ordered bf16 ea (K pad 32)
    float* pe    = (float*)carve((size_t)NE * 4 * 4);     // 8 MB, exp(score) per edge x head

    short* C2 = C1;                                  // stride 256, reuse after layer 1

    const int NB = (NN + 255) / 256;                 // 196

    // ---- CSR build ----
    hipMemsetAsync(cur, 0, (size_t)NN * 4, stream);
    k_count<<<(NE + 255) / 256, 256, 0, stream>>>(dstv, cur);
    k_scan1<<<NB, 256, 0, stream>>>(cur, off, bsum);
    k_scan2<<<1, 256, 0, stream>>>(bsum, NB);
    k_scan3c<<<(NN + 256) / 256, 256, 0, stream>>>(off, bsum, cur);
    k_scatter<<<(NE + 255) / 256, 256, 0, stream>>>(srcv, dstv, cur, srcp, dstp, ey);

    // ---- prep ----
    k_cvt_x<<<((size_t)NN * KP1 + 255) / 256, 256, 0, stream>>>(x, xb);
    int prep_total = 384 * KP1 + 256 * 128 + 128 * 128 + 384 + 256 + 2 * 128 * 32 + 2 * 16 * 128;
    k_prep_w<<<(prep_total + 255) / 256, 256, 0, stream>>>(Wl1, Wr1, Wres, Wl2, Wr2, Wout,
                                                           bl1, br1, bres, bl2, br2,
                                                           We1, We2, att1, att2,
                                                           Wt1, Wt2, Wt3, bcat1, bcat2,
                                                           WeT1, WeT2, attB1, attB2);
    k_gather_ea<<<(NE + 255) / 256, 256, 0, stream>>>(ey, ea, eaperm);

    int mb  = (NN + 127) / 128;                      // 391
    int ebk = (NE + 127) / 128;                      // 3907
    int gagg = (NN + 15) / 16;                       // 3125 blocks (4 waves x 4 nodes)

    // ---- layer 1 ----
    k_mfma_gemm<true><<<dim3(mb, 3), 256, 0, stream>>>(xb, Wt1, bcat1, nullptr, C1, NN, KP1, 384);
    k_edge_score<384><<<ebk, 256, 0, stream>>>(eaperm, WeT1, attB1, srcp, dstp, C1, pe);
    k_fused_agg<384><<<gagg, 256, 0, stream>>>(off, srcp, pe, C1,
                                               C1 + 256, 384, bias1, g1, bn1, h1b);
    // ---- layer 2 ----
    k_mfma_gemm<true><<<dim3(mb, 2), 256, 0, stream>>>(h1b, Wt2, bcat2, nullptr, C2, NN, 128, 256);
    k_edge_score<256><<<ebk, 256, 0, stream>>>(eaperm, WeT2, attB2, srcp, dstp, C2, pe);
    k_fused_agg<256><<<gagg, 256, 0, stream>>>(off, srcp, pe, C2,
                                               h1b, 128, bias2, g2, bn2, h2b);
    // ---- output: GEMM + fused LN ----
    k_gemm_ln<<<mb, 256, 0, stream>>>(h2b, Wt3, bout, go, bo, outp, NN);
}